// Round 5
// baseline (509.636 us; speedup 1.0000x reference)
//
#include <hip/hip_runtime.h>

// MHA forward. f32 in/out; bf16 MFMA compute (16x16x32), fp32 accum.
// Pipeline: cvt_x (f32->bf16) + transposeW -> GEMM Q/K (mode1) / V (mode2, V^T)
//           -> flash attention (128-row Q-tiles, Q in regs) -> GEMM out (f32).
// Workspace (u16): WqT..WoT 4x1M, xb/Ctx 8M (aliased), Q,K,Vt 8M each = 72 MB.
//
// R5 vs R4: (1) attention: 128-row Q tile, Q in registers, 2 barriers/iter
// (wave-private P hop w/ lgkmcnt wait), pad +4, launch_bounds(256,4) -> 4 blk/CU.
// (2) GEMMs all-bf16 w/ global_load_lds width-16 (m97); x pre-converted once.

typedef unsigned short u16;
typedef __attribute__((ext_vector_type(8))) short short8;   // 8 bf16
typedef __attribute__((ext_vector_type(4))) float floatx4;  // 4 fp32

#define NEG_BIG (-1e30f)

__device__ __forceinline__ u16 f2bf(float f) {
  unsigned int u = __builtin_bit_cast(unsigned int, f);
  u += 0x7fffu + ((u >> 16) & 1u);
  return (u16)(u >> 16);
}

__device__ __forceinline__ short8 cvt8(const float* __restrict__ p) {
  const floatx4 a = *(const floatx4*)p;
  const floatx4 b = *(const floatx4*)(p + 4);
  short8 r;
  r[0] = (short)f2bf(a[0]); r[1] = (short)f2bf(a[1]);
  r[2] = (short)f2bf(a[2]); r[3] = (short)f2bf(a[3]);
  r[4] = (short)f2bf(b[0]); r[5] = (short)f2bf(b[1]);
  r[6] = (short)f2bf(b[2]); r[7] = (short)f2bf(b[3]);
  return r;
}

// async global->LDS, 16B/lane; LDS dest = wave-uniform base + lane*16 [m97/m104]
__device__ __forceinline__ void gll16(const u16* g, u16* l) {
  __builtin_amdgcn_global_load_lds((const __attribute__((address_space(1))) void*)g,
                                   (__attribute__((address_space(3))) void*)l,
                                   16, 0, 0);
}

// ---------------------------------------------------------------------------
__global__ void cvt_x(const float* __restrict__ x, u16* __restrict__ xb) {
  const int i = blockIdx.x * 256 + threadIdx.x;  // 8 elems each
  *(short8*)(xb + (size_t)i * 8) = cvt8(x + (size_t)i * 8);
}

// ---------------------------------------------------------------------------
// 1024x1024 transpose + f32->bf16 (x4 matrices via grid.z).
__global__ void transpose4(const float* __restrict__ s0, const float* __restrict__ s1,
                           const float* __restrict__ s2, const float* __restrict__ s3,
                           u16* __restrict__ d0, u16* __restrict__ d1,
                           u16* __restrict__ d2, u16* __restrict__ d3) {
  __shared__ u16 tile[64][72];
  const float* src; u16* dst;
  switch (blockIdx.z) {
    case 0: src = s0; dst = d0; break;
    case 1: src = s1; dst = d1; break;
    case 2: src = s2; dst = d2; break;
    default: src = s3; dst = d3; break;
  }
  const int t = threadIdx.x;
  const int c = t & 63, rg = t >> 6;
  const int x0 = blockIdx.x * 64, y0 = blockIdx.y * 64;
#pragma unroll
  for (int i = 0; i < 16; ++i) {
    const int row = rg * 16 + i;
    tile[row][c] = f2bf(src[(size_t)(y0 + row) * 1024 + x0 + c]);
  }
  __syncthreads();
#pragma unroll
  for (int i = 0; i < 16; ++i) {
    const int row = rg * 16 + i;
    dst[(size_t)(x0 + row) * 1024 + y0 + c] = tile[c][row];
  }
}

// ---------------------------------------------------------------------------
// C[M,N] = A[M,K] @ Bt[N,K]^T + bias[N]; bf16 A/Bt; 128x128 tile, BK=32, m97.
// MODE 0: C f32 row-major; MODE 1: bf16 [b,h,l,dh]; MODE 2: bf16 [b,h,dh,l].
template <int MODE>
__global__ __launch_bounds__(256, 2) void gemm_bt(
    const u16* __restrict__ A, const u16* __restrict__ Bt,
    const float* __restrict__ bias, void* __restrict__ Cp, int M, int N, int K) {
  __shared__ __align__(16) u16 As[128 * 32];
  __shared__ __align__(16) u16 Bs[128 * 32];
  const int t = threadIdx.x;
  const int w = t >> 6, l = t & 63;
  const int quad = l >> 4, l16 = l & 15;
  const int m0 = blockIdx.y * 128, n0 = blockIdx.x * 128;
  const int wr = w >> 1, wc = w & 1;

  floatx4 acc[4][4] = {};

  for (int k0 = 0; k0 < K; k0 += 32) {
    __syncthreads();
#pragma unroll
    for (int p = 0; p < 2; ++p) {
      const int c0 = (p * 4 + w) * 64;
      const int c = c0 + l;
      const int row = c >> 2;
      const int koff = (c & 3) * 8;
      gll16(A + (size_t)(m0 + row) * K + k0 + koff, &As[c0 * 8]);
      gll16(Bt + (size_t)(n0 + row) * K + k0 + koff, &Bs[c0 * 8]);
    }
    __syncthreads();  // vmcnt(0) drain: staged data visible

    short8 af[4], bf[4];
#pragma unroll
    for (int i = 0; i < 4; ++i)
      af[i] = *(const short8*)&As[(wr * 64 + i * 16 + l16) * 32 + quad * 8];
#pragma unroll
    for (int j = 0; j < 4; ++j)
      bf[j] = *(const short8*)&Bs[(wc * 64 + j * 16 + l16) * 32 + quad * 8];
#pragma unroll
    for (int i = 0; i < 4; ++i)
#pragma unroll
      for (int j = 0; j < 4; ++j)
        acc[i][j] = __builtin_amdgcn_mfma_f32_16x16x32_bf16(af[i], bf[j], acc[i][j], 0, 0, 0);
  }

  // Epilogue: C/D layout col=lane&15, row=quad*4+reg [m89/m91]
#pragma unroll
  for (int j = 0; j < 4; ++j) {
    const int n = n0 + wc * 64 + j * 16 + l16;
    const float bv = bias[n];
#pragma unroll
    for (int i = 0; i < 4; ++i) {
      const int rb = m0 + wr * 64 + i * 16 + quad * 4;
#pragma unroll
      for (int r = 0; r < 4; ++r) {
        const int m = rb + r;
        const float v = acc[i][j][r] + bv;
        if (MODE == 0) {
          ((float*)Cp)[(size_t)m * N + n] = v;
        } else {
          const int b = m >> 11, ll = m & 2047, h = n >> 6, dh = n & 63;
          size_t idx;
          if (MODE == 1) idx = ((size_t)(b * 16 + h) * 2048 + ll) * 64 + dh;
          else           idx = ((size_t)(b * 16 + h) * 64 + dh) * 2048 + ll;
          ((u16*)Cp)[idx] = f2bf(v);
        }
      }
    }
  }
}

// ---------------------------------------------------------------------------
// Flash attention, causal. Block = (b*16+h, 128-row q-tile); wave owns 32 rows
// (2 m-frags, Q in registers). K-tile 64. Q,K:[b,h,l,dh]; Vt:[b,h,dh,l];
// ctx:[b,l,h*64+dh] bf16. LDS stride 68 (+4 pad): all hot accesses <=2-way.
#define ATT_STRIDE 68
__global__ __launch_bounds__(256, 4) void attn_kernel(
    const u16* __restrict__ Q, const u16* __restrict__ K,
    const u16* __restrict__ Vt, u16* __restrict__ ctx) {
  __shared__ __align__(16) u16 Ks[64 * ATT_STRIDE];
  __shared__ __align__(16) u16 Vs[64 * ATT_STRIDE];          // V^T tile [d][k]
  __shared__ __align__(16) u16 Ps[4 * 32 * ATT_STRIDE];      // per-wave P hop

  const int t = threadIdx.x;
  const int w = t >> 6, l = t & 63;
  const int quad = l >> 4, l16 = l & 15;
  const int qt = gridDim.x - 1 - blockIdx.x;  // heavy tiles dispatched first
  const int bh = blockIdx.y;
  const int q0 = qt * 128;
  const int nkt = 2 * qt + 2;
  const size_t qkbase = (size_t)bh * (2048 * 64);
  u16* Pw = &Ps[w * 32 * ATT_STRIDE];

  // Q fragments in registers: A-layout, rows w*32+mf*16+l16, k = ks*32+quad*8
  short8 aq[2][2];
#pragma unroll
  for (int mf = 0; mf < 2; ++mf)
#pragma unroll
    for (int ks = 0; ks < 2; ++ks)
      aq[mf][ks] = *(const short8*)(Q + qkbase +
          (size_t)(q0 + w * 32 + mf * 16 + l16) * 64 + ks * 32 + quad * 8);

  floatx4 o[2][4] = {};
  float mrow[2][4], lrow[2][4];
#pragma unroll
  for (int mf = 0; mf < 2; ++mf)
#pragma unroll
    for (int r = 0; r < 4; ++r) { mrow[mf][r] = NEG_BIG; lrow[mf][r] = 0.f; }

  for (int kt = 0; kt < nkt; ++kt) {
    const int k0 = kt * 64;
    __syncthreads();  // prev-iter K/V reads done before overwrite
#pragma unroll
    for (int c = t; c < 512; c += 256) {
      const int row = c >> 3, cc = c & 7;
      *(short8*)&Ks[row * ATT_STRIDE + cc * 8] =
          *(const short8*)(K + qkbase + (size_t)(k0 + row) * 64 + cc * 8);
      *(short8*)&Vs[row * ATT_STRIDE + cc * 8] =
          *(const short8*)(Vt + qkbase + (size_t)row * 2048 + k0 + cc * 8);
    }
    __syncthreads();  // staged K/V visible

    // S = Q K^T : 16 MFMA
    floatx4 s[2][4] = {};
#pragma unroll
    for (int ks = 0; ks < 2; ++ks)
#pragma unroll
      for (int tn = 0; tn < 4; ++tn) {
        const short8 bk = *(const short8*)&Ks[(tn * 16 + l16) * ATT_STRIDE + ks * 32 + quad * 8];
#pragma unroll
        for (int mf = 0; mf < 2; ++mf)
          s[mf][tn] = __builtin_amdgcn_mfma_f32_16x16x32_bf16(aq[mf][ks], bk, s[mf][tn], 0, 0, 0);
      }

    // scale + causal mask (only the last two k-tiles intersect the diagonal)
    const bool maskable = (k0 + 63 > q0);
#pragma unroll
    for (int mf = 0; mf < 2; ++mf)
#pragma unroll
      for (int tn = 0; tn < 4; ++tn)
#pragma unroll
        for (int r = 0; r < 4; ++r) {
          float v = s[mf][tn][r] * 0.125f;  // 1/sqrt(64)
          if (maskable &&
              (k0 + tn * 16 + l16 > q0 + w * 32 + mf * 16 + quad * 4 + r))
            v = NEG_BIG;
          s[mf][tn][r] = v;
        }

    // online softmax (rows live across one quad's 16 lanes)
#pragma unroll
    for (int mf = 0; mf < 2; ++mf) {
      float alpha[4];
#pragma unroll
      for (int r = 0; r < 4; ++r) {
        float mx = fmaxf(fmaxf(s[mf][0][r], s[mf][1][r]),
                         fmaxf(s[mf][2][r], s[mf][3][r]));
#pragma unroll
        for (int off = 8; off >= 1; off >>= 1)
          mx = fmaxf(mx, __shfl_xor(mx, off, 16));
        const float mnew = fmaxf(mrow[mf][r], mx);
        alpha[r] = __expf(mrow[mf][r] - mnew);
        mrow[mf][r] = mnew;
        float rs = 0.f;
#pragma unroll
        for (int tn = 0; tn < 4; ++tn) {
          const float p = __expf(s[mf][tn][r] - mnew);
          s[mf][tn][r] = p;
          rs += p;
        }
#pragma unroll
        for (int off = 8; off >= 1; off >>= 1)
          rs += __shfl_xor(rs, off, 16);
        lrow[mf][r] = lrow[mf][r] * alpha[r] + rs;
      }
#pragma unroll
      for (int td = 0; td < 4; ++td)
#pragma unroll
        for (int r = 0; r < 4; ++r) o[mf][td][r] *= alpha[r];
    }

    // P: C-layout -> wave-private LDS -> A-layout (no block barrier needed)
#pragma unroll
    for (int mf = 0; mf < 2; ++mf)
#pragma unroll
      for (int tn = 0; tn < 4; ++tn)
#pragma unroll
        for (int r = 0; r < 4; ++r)
          Pw[(mf * 16 + quad * 4 + r) * ATT_STRIDE + tn * 16 + l16] = f2bf(s[mf][tn][r]);
    __asm__ volatile("s_waitcnt lgkmcnt(0)" ::: "memory");  // wave-level drain
    __builtin_amdgcn_wave_barrier();                        // no compiler reorder

    // O += P V : 16 MFMA
#pragma unroll
    for (int ks = 0; ks < 2; ++ks) {
      short8 ap[2];
#pragma unroll
      for (int mf = 0; mf < 2; ++mf)
        ap[mf] = *(const short8*)&Pw[(mf * 16 + l16) * ATT_STRIDE + ks * 32 + quad * 8];
#pragma unroll
      for (int td = 0; td < 4; ++td) {
        const short8 bv = *(const short8*)&Vs[(td * 16 + l16) * ATT_STRIDE + ks * 32 + quad * 8];
#pragma unroll
        for (int mf = 0; mf < 2; ++mf)
          o[mf][td] = __builtin_amdgcn_mfma_f32_16x16x32_bf16(ap[mf], bv, o[mf][td], 0, 0, 0);
      }
    }
  }

  // normalize + store ctx[b, l, h*64+dh] (bf16)
  const int b = bh >> 4, h = bh & 15;
#pragma unroll
  for (int mf = 0; mf < 2; ++mf)
#pragma unroll
    for (int r = 0; r < 4; ++r) {
      const float inv = 1.f / lrow[mf][r];
      const int gq = q0 + w * 32 + mf * 16 + quad * 4 + r;
      const size_t rowbase = ((size_t)(b * 2048 + gq)) * 1024 + h * 64;
#pragma unroll
      for (int td = 0; td < 4; ++td)
        ctx[rowbase + td * 16 + l16] = f2bf(o[mf][td][r] * inv);
    }
}

// ---------------------------------------------------------------------------
extern "C" void kernel_launch(void* const* d_in, const int* in_sizes, int n_in,
                              void* d_out, int out_size, void* d_ws, size_t ws_size,
                              hipStream_t stream) {
  const float* x  = (const float*)d_in[0];
  // d_in[1] = attn_mask (causal tril) — implemented analytically
  const float* Wq = (const float*)d_in[2];
  const float* bq = (const float*)d_in[3];
  const float* Wk = (const float*)d_in[4];
  const float* bk = (const float*)d_in[5];
  const float* Wv = (const float*)d_in[6];
  const float* bv = (const float*)d_in[7];
  const float* Wo = (const float*)d_in[8];
  const float* bo = (const float*)d_in[9];

  u16* ws = (u16*)d_ws;
  const size_t WSZ = 1u << 20;   // 1024*1024
  const size_t TSZ = 8u << 20;   // 8192*1024
  u16* WqT = ws;
  u16* WkT = ws + WSZ;
  u16* WvT = ws + 2 * WSZ;
  u16* WoT = ws + 3 * WSZ;
  u16* xb  = ws + 4 * WSZ;       // x as bf16; reused as Ctx after attention
  u16* Qb  = xb + TSZ;
  u16* Kb  = Qb + TSZ;
  u16* Vtb = Kb + TSZ;
  u16* Ctx = xb;                 // alias: x no longer needed post-QKV

  const dim3 tb(256);
  cvt_x<<<dim3(4096), tb, 0, stream>>>(x, xb);
  transpose4<<<dim3(16, 16, 4), tb, 0, stream>>>(Wq, Wk, Wv, Wo, WqT, WkT, WvT, WoT);
  gemm_bt<1><<<dim3(8, 64), tb, 0, stream>>>(xb, WqT, bq, Qb, 8192, 1024, 1024);
  gemm_bt<1><<<dim3(8, 64), tb, 0, stream>>>(xb, WkT, bk, Kb, 8192, 1024, 1024);
  gemm_bt<2><<<dim3(8, 64), tb, 0, stream>>>(xb, WvT, bv, Vtb, 8192, 1024, 1024);
  attn_kernel<<<dim3(16, 64), tb, 0, stream>>>(Qb, Kb, Vtb, Ctx);
  gemm_bt<0><<<dim3(8, 64), tb, 0, stream>>>(Ctx, WoT, bo, (float*)d_out, 8192, 1024, 1024);
}